// Round 2
// 217.622 us; speedup vs baseline: 1.0911x; 1.0911x over previous
//
#include <hip/hip_runtime.h>
#include <hip/hip_fp16.h>
#include <math.h>

#define HH 256
#define WW 256
#define CTOT 256
#define HW (HH * WW)
#define NBIN 49

typedef __attribute__((ext_vector_type(8))) _Float16 half8;
typedef __attribute__((ext_vector_type(4))) float fvec4;

// ---------- pass 1: (B,256,H,W) f32 -> (B,32,H,W,8) f16 orientation-interleaved ----------
// v3: ONE pixel per thread. Loads: 4 B/lane fully coalesced (256 B/instr).
// Store: one half8 = 16 B/lane fully coalesced (1 KiB/instr).  The previous
// 4-px/thread version scattered every store instruction across 64 cache lines
// (64 B inter-lane stride), which is the suspected convert-pass bottleneck.
__global__ __launch_bounds__(256) void convert_kernel_v3(
    const float* __restrict__ feats, half8* __restrict__ wsf, int total /* B*32*HW */)
{
    const int g = blockIdx.x * 256 + threadIdx.x;
    if (g >= total) return;
    const int pix = g & (HW - 1);            // HW = 65536
    const int bc  = g >> 16;                 // b*32 + c
    const float* src = feats + ((size_t)bc * 8) * HW + pix;
    half8 h;
    #pragma unroll
    for (int o = 0; o < 8; ++o)
        h[o] = (_Float16)__builtin_nontemporal_load(src + (size_t)o * HW);
    wsf[(size_t)bc * HW + pix] = h;
}

// ---------- pass 2: one thread = (cg, roi, bin, sample s) ----------
// v4: XCD-aware cg blocking.  bid&7 ~ XCD; each XCD owns 4 cg planes and
// processes them one at a time, so the live gather working set per XCD is
// ~one cg plane-pair (2 MiB) < 4 MiB L2 -> bilinear gathers become L2 hits
// instead of L3/HBM traffic.
__global__ __launch_bounds__(256) void riroi_pool_f16_v4(
    const half8* __restrict__ wsf,     // (B, 32, HW) of half8
    const float* __restrict__ rois,
    float* __restrict__ out,           // (n_rois, 256, 7, 7)
    int per_cg4,                       // n_rois * 49 * 4
    int nxblk)                         // blocks per cg = ceil(per_cg4/256)
{
    const int bid  = blockIdx.x;
    const int xcd  = bid & 7;
    const int idx  = bid >> 3;               // 0 .. 4*nxblk-1
    const int cgq  = idx / nxblk;            // 0..3
    const int xblk = idx - cgq * nxblk;
    const int cg   = (xcd << 2) + cgq;       // channel group 0..31
    const int h    = xblk * 256 + threadIdx.x;
    if (h >= per_cg4) return;

    const int s   = h & 3;             // sample: gy = s>>1, gx = s&1
    const int t   = h >> 2;
    const int n   = t / NBIN;
    const int bin = t - n * NBIN;
    const int ph  = bin / 7;
    const int pw  = bin - ph * 7;

    const float2 r01 = *(const float2*)(rois + n * 6);
    const float2 r23 = *(const float2*)(rois + n * 6 + 2);
    const float2 r45 = *(const float2*)(rois + n * 6 + 4);
    const int   b     = (int)r01.x;
    const float cx    = r01.y * 0.25f;
    const float cy    = r23.x * 0.25f;
    const float rwv   = fmaxf(r23.y * 0.25f, 1.0f);
    const float rhv   = fmaxf(r45.x * 0.25f, 1.0f);
    const float theta = r45.y;
    const float bin_h = rhv * (1.0f / 7.0f);
    const float bin_w = rwv * (1.0f / 7.0f);

    const float ind_f = (theta * 8.0f) / 6.28318530717958647692f;
    const int   ind0  = (int)floorf(ind_f);
    const float l_var = ind_f - (float)ind0;
    const float r_var = 1.0f - l_var;
    const int   ind   = ((ind0 % 8) + 8) % 8;
    float sin_t, cos_t;
    sincosf(theta, &sin_t, &cos_t);    // CLOCKWISE=false

    // ---- geometry for this thread's single sample ----
    const int gy = s >> 1, gx = s & 1;
    const float yy = -rhv * 0.5f + ((float)ph + ((float)gy + 0.5f) * 0.5f) * bin_h;
    const float xx = -rwv * 0.5f + ((float)pw + ((float)gx + 0.5f) * 0.5f) * bin_w;
    const float y  = yy * cos_t - xx * sin_t + cy;
    const float x  = yy * sin_t + xx * cos_t + cx;
    const float valid =
        (y >= -1.0f && y <= 256.0f && x >= -1.0f && x <= 256.0f) ? 1.0f : 0.0f;
    const float yc = fmaxf(y, 0.0f);
    const float xc = fmaxf(x, 0.0f);
    const int y0 = min((int)floorf(yc), HH - 1);
    const int x0 = min((int)floorf(xc), WW - 1);
    const int y1 = min(y0 + 1, HH - 1);
    const float ly = (y0 >= HH - 1) ? 0.0f : (yc - (float)y0);
    const float lx = (x0 >= WW - 1) ? 0.0f : (xc - (float)x0);
    const float hy = 1.0f - ly, hx = 1.0f - lx;
    const float sc = 0.25f * valid;            // fold sample mean + validity
    const int   xb = min(x0, WW - 2);          // pair base (xb, xb+1) in-bounds
    const float cw0 = (x0 < WW - 1) ? hx : 0.0f;   // x0==255 -> value sits at .y slot
    const float cw1 = (x0 < WW - 1) ? lx : hx;
    const float w00 = hy * sc * cw0;
    const float w01 = hy * sc * cw1;
    const float w10 = ly * sc * cw0;
    const float w11 = ly * sc * cw1;
    const int off0 = (y0 << 8) + xb;
    const int off1 = (y1 << 8) + xb;

    const half8* base = wsf + (size_t)(b * 32 + cg) * HW;

    // 4 independent 16B loads (now mostly L2-resident thanks to cg blocking)
    const half8 q0 = base[off0];
    const half8 q1 = base[off0 + 1];
    const half8 q2 = base[off1];
    const half8 q3 = base[off1 + 1];

    float acc[8];
    #pragma unroll
    for (int o = 0; o < 8; ++o)
        acc[o] = w00 * (float)q0[o] + w01 * (float)q1[o]
               + w10 * (float)q2[o] + w11 * (float)q3[o];

    // combine the 4 samples of this bin (lane quads aligned & co-active)
    #pragma unroll
    for (int o = 0; o < 8; ++o) {
        acc[o] += __shfl_xor(acc[o], 1, 64);
        acc[o] += __shfl_xor(acc[o], 2, 64);
    }

    // ---- orientation mix; lane s stores outputs k=2s, 2s+1 (static indices) ----
    float* obase = out + ((size_t)n * CTOT + (size_t)(cg * 8)) * NBIN + bin;
    switch (s) {
    case 0:
        __builtin_nontemporal_store(r_var * acc[0] + l_var * acc[1], obase + (((0 + ind) & 7) * NBIN));
        __builtin_nontemporal_store(r_var * acc[1] + l_var * acc[2], obase + (((1 + ind) & 7) * NBIN));
        break;
    case 1:
        __builtin_nontemporal_store(r_var * acc[2] + l_var * acc[3], obase + (((2 + ind) & 7) * NBIN));
        __builtin_nontemporal_store(r_var * acc[3] + l_var * acc[4], obase + (((3 + ind) & 7) * NBIN));
        break;
    case 2:
        __builtin_nontemporal_store(r_var * acc[4] + l_var * acc[5], obase + (((4 + ind) & 7) * NBIN));
        __builtin_nontemporal_store(r_var * acc[5] + l_var * acc[6], obase + (((5 + ind) & 7) * NBIN));
        break;
    default:
        __builtin_nontemporal_store(r_var * acc[6] + l_var * acc[7], obase + (((6 + ind) & 7) * NBIN));
        __builtin_nontemporal_store(r_var * acc[7] + l_var * acc[0], obase + (((7 + ind) & 7) * NBIN));
        break;
    }
}

// ---------- fallback if workspace too small ----------
__global__ __launch_bounds__(256) void riroi_rotated_fallback(
    const float* __restrict__ feats, const float* __restrict__ rois,
    float* __restrict__ out, int total)
{
    const int g = blockIdx.x * 256 + threadIdx.x;
    if (g >= total) return;
    const int wpr = 32 * NBIN;
    const int n   = g / wpr;
    const int rem = g - n * wpr;
    const int cg  = rem / NBIN;
    const int bin = rem - cg * NBIN;
    const int ph  = bin / 7;
    const int pw  = bin - ph * 7;
    const float* r = rois + n * 6;
    const int   b     = (int)r[0];
    const float cx    = r[1] * 0.25f;
    const float cy    = r[2] * 0.25f;
    const float rwv   = fmaxf(r[3] * 0.25f, 1.0f);
    const float rhv   = fmaxf(r[4] * 0.25f, 1.0f);
    const float theta = r[5];
    const float bin_h = rhv * (1.0f / 7.0f);
    const float bin_w = rwv * (1.0f / 7.0f);
    const float ind_f = (theta * 8.0f) / 6.28318530717958647692f;
    const int   ind0  = (int)floorf(ind_f);
    const float l_var = ind_f - (float)ind0;
    const float r_var = 1.0f - l_var;
    const int   ind   = ((ind0 % 8) + 8) % 8;
    const float cos_t = cosf(theta);
    const float sin_t = sinf(theta);
    int   off0[4], off1[4];
    float rw0[4], rw1[4], cw0[4], cw1[4];
    #pragma unroll
    for (int s = 0; s < 4; ++s) {
        const int gy = s >> 1, gx = s & 1;
        const float yy = -rhv * 0.5f + ((float)ph + ((float)gy + 0.5f) * 0.5f) * bin_h;
        const float xx = -rwv * 0.5f + ((float)pw + ((float)gx + 0.5f) * 0.5f) * bin_w;
        const float y  = yy * cos_t - xx * sin_t + cy;
        const float x  = yy * sin_t + xx * cos_t + cx;
        const float valid =
            (y >= -1.0f && y <= 256.0f && x >= -1.0f && x <= 256.0f) ? 1.0f : 0.0f;
        const float yc = fmaxf(y, 0.0f);
        const float xc = fmaxf(x, 0.0f);
        const int y0 = min((int)floorf(yc), HH - 1);
        const int x0 = min((int)floorf(xc), WW - 1);
        const int y1 = min(y0 + 1, HH - 1);
        const float ly = (y0 >= HH - 1) ? 0.0f : (yc - (float)y0);
        const float lx = (x0 >= WW - 1) ? 0.0f : (xc - (float)x0);
        const float hy = 1.0f - ly, hx = 1.0f - lx;
        const float sc = 0.25f * valid;
        const int   xb = min(x0, WW - 2);
        cw0[s]  = (x0 < WW - 1) ? hx : 0.0f;
        cw1[s]  = (x0 < WW - 1) ? lx : hx;
        rw0[s]  = hy * sc;
        rw1[s]  = ly * sc;
        off0[s] = (y0 << 8) + xb;
        off1[s] = (y1 << 8) + xb;
    }
    const float* gbase = feats + (size_t)b * (CTOT * HW) + (size_t)(cg * 8) * HW;
    float acc[8];
    #pragma unroll
    for (int o = 0; o < 8; o += 2) {
        const float* pA = gbase + (size_t)o * HW;
        const float* pB = pA + HW;
        float2 q[16];
        #pragma unroll
        for (int s = 0; s < 4; ++s) {
            q[s * 4 + 0] = *(const float2*)(pA + off0[s]);
            q[s * 4 + 1] = *(const float2*)(pA + off1[s]);
            q[s * 4 + 2] = *(const float2*)(pB + off0[s]);
            q[s * 4 + 3] = *(const float2*)(pB + off1[s]);
        }
        float a0 = 0.0f, a1 = 0.0f;
        #pragma unroll
        for (int s = 0; s < 4; ++s) {
            a0 += rw0[s] * (cw0[s] * q[s * 4 + 0].x + cw1[s] * q[s * 4 + 0].y)
                + rw1[s] * (cw0[s] * q[s * 4 + 1].x + cw1[s] * q[s * 4 + 1].y);
            a1 += rw0[s] * (cw0[s] * q[s * 4 + 2].x + cw1[s] * q[s * 4 + 2].y)
                + rw1[s] * (cw0[s] * q[s * 4 + 3].x + cw1[s] * q[s * 4 + 3].y);
        }
        acc[o] = a0; acc[o + 1] = a1;
    }
    float* obase = out + ((size_t)n * CTOT + (size_t)(cg * 8)) * NBIN + bin;
    #pragma unroll
    for (int s = 0; s < 8; ++s) {
        const int o_out = (s + ind) & 7;
        __builtin_nontemporal_store(r_var * acc[s] + l_var * acc[(s + 1) & 7],
                                    obase + o_out * NBIN);
    }
}

extern "C" void kernel_launch(void* const* d_in, const int* in_sizes, int n_in,
                              void* d_out, int out_size, void* d_ws, size_t ws_size,
                              hipStream_t stream) {
    const float* feats = (const float*)d_in[0];
    const float* rois  = (const float*)d_in[1];
    float* out = (float*)d_out;
    const int n_rois = in_sizes[1] / 6;
    const int B      = in_sizes[0] / (CTOT * HW);
    const size_t ws_need = (size_t)B * 32 * HW * sizeof(half8);

    if (ws_size >= ws_need) {
        half8* wsf = (half8*)d_ws;
        const int total = B * 32 * HW;
        convert_kernel_v3<<<(total + 255) / 256, 256, 0, stream>>>(feats, wsf, total);
        const int per_cg4 = n_rois * NBIN * 4;
        const int nxblk   = (per_cg4 + 255) / 256;   // blocks per cg
        dim3 grid(32 * nxblk);
        riroi_pool_f16_v4<<<grid, 256, 0, stream>>>(wsf, rois, out, per_cg4, nxblk);
    } else {
        const int total = n_rois * 32 * NBIN;
        riroi_rotated_fallback<<<(total + 255) / 256, 256, 0, stream>>>(feats, rois, out, total);
    }
}